// Round 4
// baseline (167.604 us; speedup 1.0000x reference)
//
#include <hip/hip_runtime.h>
#include <hip/hip_bf16.h>

#define T_  256
#define NN_ 2048

typedef short bf16x8 __attribute__((ext_vector_type(8)));
typedef float f32x4  __attribute__((ext_vector_type(4)));

__device__ __forceinline__ unsigned short f2bf(float x) {
    union { float f; unsigned u; } v; v.f = x;
    unsigned r = v.u + 0x7fffu + ((v.u >> 16) & 1u);   // RTNE, finite inputs
    return (unsigned short)(r >> 16);
}
__device__ __forceinline__ float bflo(unsigned w) {
    union { unsigned u; float f; } v; v.u = w << 16; return v.f;
}
__device__ __forceinline__ float bfhi(unsigned w) {
    union { unsigned u; float f; } v; v.u = w & 0xffff0000u; return v.f;
}
__device__ __forceinline__ unsigned pkbf(float lo, float hi) {
    union { __hip_bfloat16 h; unsigned short s; } a, b;
    a.h = __float2bfloat16(lo);
    b.h = __float2bfloat16(hi);
    return (unsigned)a.s | ((unsigned)b.s << 16);
}

// ---------------------------------------------------------------------------
// cs[p*512+f] = packed bf16 (cos,sin) of 2*pi*frac(p * 10000^(-f/512)).
// 32 KB -> L1-resident.  Token t, channel n: pos = (bit9(n)? t&15 : t>>4),
// f = n & 511  ([ph_h|ph_w|ph_h|ph_w] repeats with period 1024).
// ---------------------------------------------------------------------------
__global__ void build_cs(unsigned* __restrict__ cs) {
    int idx = blockIdx.x * 256 + threadIdx.x;     // 8192 entries
    int p = idx >> 9, f = idx & 511;
    float inv = powf(10000.0f, -(float)f * (1.0f / 512.0f));
    float ph  = (float)p * inv;
    float ang = (ph - floorf(ph)) * 6.28318530717958647692f;
    float s, c;
    sincosf(ang, &s, &c);
    cs[idx] = pkbf(c, s);
}

// ---------------------------------------------------------------------------
// vtrans: V fp32 (16,256,256) -> Vt bf16 [b][d][s]  (2.1 MB, L2/L3-resident).
// 64x64 tiles through LDS.
// ---------------------------------------------------------------------------
__global__ void vtrans(const float* __restrict__ V, unsigned short* __restrict__ Vt) {
    __shared__ unsigned short Tl[64 * 72];
    const int tid = threadIdx.x;
    const int b  = blockIdx.x >> 4;
    const int s0 = ((blockIdx.x >> 2) & 3) << 6;
    const int d0 = (blockIdx.x & 3) << 6;
    const float* Vb = V + (size_t)b * 65536;
#pragma unroll
    for (int u = 0; u < 4; u++) {
        int lin = u * 256 + tid;
        int srow = lin >> 4, c4 = (lin & 15) << 2;
        float4 v = *(const float4*)(Vb + (size_t)(s0 + srow) * 256 + d0 + c4);
        Tl[(c4 + 0) * 72 + srow] = f2bf(v.x);
        Tl[(c4 + 1) * 72 + srow] = f2bf(v.y);
        Tl[(c4 + 2) * 72 + srow] = f2bf(v.z);
        Tl[(c4 + 3) * 72 + srow] = f2bf(v.w);
    }
    __syncthreads();
    unsigned short* Vtb = Vt + (size_t)b * 65536;
#pragma unroll
    for (int u = 0; u < 2; u++) {
        int lin = u * 256 + tid;
        int drow = lin >> 3, sc8 = (lin & 7) << 3;
        *(uint4*)(Vtb + (size_t)(d0 + drow) * 256 + s0 + sc8) =
            *(const uint4*)(&Tl[drow * 72 + sc8]);
    }
}

// ---------------------------------------------------------------------------
// gemm1: scores = RoPE(Q).RoPE(K)^T / sqrt(N).
// 128x64 tile, BK=64, 512 threads (8 waves), 512 blocks = 2 blocks/CU
// = 16 waves/CU.  Depth-2 Q/K register prefetch, single-set cs prefetch,
// lgkm-only barrier (global loads stay in flight), setprio around MFMA.
// ---------------------------------------------------------------------------
struct QKSet { float4 a[4]; float4 b[2]; };
struct CSet  { uint4  a[4]; uint4  b[2]; };

__launch_bounds__(512, 4)
__global__ void gemm1(const float* __restrict__ Q, const float* __restrict__ K,
                      const unsigned* __restrict__ cs, unsigned short* __restrict__ scores) {
    __shared__ __align__(16) unsigned short Als[2][128 * 72];
    __shared__ __align__(16) unsigned short Bls[2][64 * 72];

    const int tid  = threadIdx.x;
    const int bh   = blockIdx.x & 63;          // bh%8 fixed per XCD -> L2/L3 locality
    const int tile = blockIdx.x >> 6;          // 0..7
    const int ti = (tile >> 2) << 7;           // 0,128      (Q rows)
    const int si = (tile & 3) << 6;            // 0..192     (K rows)

    const float* Qb = Q + (size_t)bh * (T_ * NN_);
    const float* Kb = K + (size_t)bh * (T_ * NN_);

    // staging geometry: thread owns 8-float octs.  A: 2 units, B: 1 unit.
    const float* qpA[2]; int cshA[2], cswA[2], ldsA[2];
    const float* qpB0;   int cshB0,  cswB0,  ldsB0;
#pragma unroll
    for (int u = 0; u < 2; u++) {
        int lin = u * 512 + tid;
        int row = lin >> 3, c8 = (lin & 7) << 3;
        int gr = ti + row;
        qpA[u]  = Qb + (size_t)gr * NN_ + c8;
        cshA[u] = ((gr >> 4) << 9) + c8;
        cswA[u] = ((gr & 15) << 9) + c8;
        ldsA[u] = row * 72 + c8;
    }
    {
        int row = tid >> 3, c8 = (tid & 7) << 3;
        int gr = si + row;
        qpB0  = Kb + (size_t)gr * NN_ + c8;
        cshB0 = ((gr >> 4) << 9) + c8;
        cswB0 = ((gr & 15) << 9) + c8;
        ldsB0 = row * 72 + c8;
    }

    const int wv = tid >> 6, lane = tid & 63;
    const int lr = lane & 15, lg = lane >> 4;
    const int m0 = (wv >> 1) << 5;             // 0,32,64,96
    const int n0 = (wv & 1) << 5;              // 0,32

    f32x4 acc[2][2];
#pragma unroll
    for (int i = 0; i < 2; i++)
#pragma unroll
        for (int j = 0; j < 2; j++) acc[i][j] = (f32x4){0.f, 0.f, 0.f, 0.f};

    auto LOAD = [&](QKSet& s, int k0) {
#pragma unroll
        for (int u = 0; u < 2; u++) {
            s.a[2*u]   = *(const float4*)(qpA[u] + k0);
            s.a[2*u+1] = *(const float4*)(qpA[u] + k0 + 4);
        }
        s.b[0] = *(const float4*)(qpB0 + k0);
        s.b[1] = *(const float4*)(qpB0 + k0 + 4);
    };

    auto CSLOAD = [&](CSet& c, int k0) {
        const int fk = k0 & 511;
        const int w  = (k0 >> 9) & 1;
#pragma unroll
        for (int u = 0; u < 2; u++) {
            const unsigned* p = cs + (w ? cswA[u] : cshA[u]) + fk;
            c.a[2*u]   = *(const uint4*)(p);
            c.a[2*u+1] = *(const uint4*)(p + 4);
        }
        const unsigned* p = cs + (w ? cswB0 : cshB0) + fk;
        c.b[0] = *(const uint4*)(p);
        c.b[1] = *(const uint4*)(p + 4);
    };

    auto ROT = [&](const float4& f0, const float4& f1,
                   const uint4& u0, const uint4& u1) -> uint4 {
        uint4 o;
        o.x = pkbf(f0.x*bflo(u0.x) - f0.y*bfhi(u0.x),
                   f0.y*bflo(u0.y) + f0.x*bfhi(u0.y));
        o.y = pkbf(f0.z*bflo(u0.z) - f0.w*bfhi(u0.z),
                   f0.w*bflo(u0.w) + f0.z*bfhi(u0.w));
        o.z = pkbf(f1.x*bflo(u1.x) - f1.y*bfhi(u1.x),
                   f1.y*bflo(u1.y) + f1.x*bfhi(u1.y));
        o.w = pkbf(f1.z*bflo(u1.z) - f1.w*bfhi(u1.z),
                   f1.w*bflo(u1.w) + f1.z*bfhi(u1.w));
        return o;
    };

    auto WRITE = [&](int buf, const QKSet& s, const CSet& c) {
#pragma unroll
        for (int u = 0; u < 2; u++)
            *(uint4*)(&Als[buf][ldsA[u]]) = ROT(s.a[2*u], s.a[2*u+1], c.a[2*u], c.a[2*u+1]);
        *(uint4*)(&Bls[buf][ldsB0]) = ROT(s.b[0], s.b[1], c.b[0], c.b[1]);
    };

    auto COMPUTE = [&](int buf) {
        __builtin_amdgcn_s_setprio(1);
#pragma unroll
        for (int kk = 0; kk < 64; kk += 32) {
            bf16x8 af[2], bfr[2];
#pragma unroll
            for (int mi = 0; mi < 2; mi++)
                af[mi] = *(const bf16x8*)(&Als[buf][(m0 + mi * 16 + lr) * 72 + kk + lg * 8]);
#pragma unroll
            for (int ni = 0; ni < 2; ni++)
                bfr[ni] = *(const bf16x8*)(&Bls[buf][(n0 + ni * 16 + lr) * 72 + kk + lg * 8]);
#pragma unroll
            for (int mi = 0; mi < 2; mi++)
#pragma unroll
                for (int ni = 0; ni < 2; ni++)
                    acc[mi][ni] = __builtin_amdgcn_mfma_f32_16x16x32_bf16(
                        af[mi], bfr[ni], acc[mi][ni], 0, 0, 0);
        }
        __builtin_amdgcn_s_setprio(0);
    };

    auto BAR = [&]() {
        asm volatile("s_waitcnt lgkmcnt(0)" ::: "memory");
        __builtin_amdgcn_s_barrier();
        asm volatile("" ::: "memory");
    };

    QKSet s0, s1; CSet c;

    LOAD(s0, 0);
    LOAD(s1, 64);
    CSLOAD(c, 0);
    WRITE(0, s0, c);
    CSLOAD(c, 64);
    BAR();

    for (int t2 = 0; t2 < 15; t2++) {
        const int t = t2 * 2;
        LOAD(s0, (t + 2) * 64);
        COMPUTE(0);                 // slab t
        WRITE(1, s1, c);            // slab t+1
        CSLOAD(c, (t + 2) * 64);
        BAR();
        LOAD(s1, (t + 3) * 64);
        COMPUTE(1);                 // slab t+1
        WRITE(0, s0, c);            // slab t+2
        CSLOAD(c, (t + 3) * 64);
        BAR();
    }
    COMPUTE(0);                     // slab 30
    WRITE(1, s1, c);                // slab 31
    BAR();
    COMPUTE(1);                     // slab 31

    // epilogue: scale, cast bf16, store scores[bh][t][s]
    const float rs = 0.02209708691207961f;   // 1/sqrt(2048)
    unsigned short* sb = scores + (size_t)bh * (T_ * T_);
#pragma unroll
    for (int mi = 0; mi < 2; mi++) {
        int tr = ti + m0 + mi * 16 + lg * 4;
#pragma unroll
        for (int ni = 0; ni < 2; ni++) {
            int sc = si + n0 + ni * 16 + lr;
#pragma unroll
            for (int r = 0; r < 4; r++)
                sb[(size_t)(tr + r) * 256 + sc] = f2bf(acc[mi][ni][r] * rs);
        }
    }
}

// ---------------------------------------------------------------------------
// gemm2: out = scores @ V.  A = scores bf16 row-major, B = Vt bf16 [d][s]
// (pre-transposed) -> both stagings are straight uint4 copies.
// 128x64 tile, 256 threads (4 waves), 512 blocks = 2 blocks/CU.
// ---------------------------------------------------------------------------
__launch_bounds__(256, 2)
__global__ void gemm2(const unsigned short* __restrict__ scores,
                      const unsigned short* __restrict__ Vt, float* __restrict__ out) {
    __shared__ __align__(16) unsigned short Als[2][128 * 72];
    __shared__ __align__(16) unsigned short Bls[2][64 * 72];

    const int tid  = threadIdx.x;
    const int bh   = blockIdx.x & 63;
    const int b    = bh >> 2;
    const int tile = blockIdx.x >> 6;          // 0..7
    const int ti = (tile >> 2) << 7;           // 0,128   (t rows)
    const int d0 = (tile & 3) << 6;            // 0..192  (d cols)

    const unsigned short* Sb  = scores + (size_t)bh * 65536;
    const unsigned short* Vtb = Vt + (size_t)b * 65536;

    const int wv = tid >> 6, lane = tid & 63;
    const int lr = lane & 15, lg = lane >> 4;
    const int m0 = (wv >> 1) * 64;
    const int n0 = (wv & 1) * 32;

    f32x4 acc[4][2];
#pragma unroll
    for (int i = 0; i < 4; i++)
#pragma unroll
        for (int j = 0; j < 2; j++) acc[i][j] = (f32x4){0.f, 0.f, 0.f, 0.f};

    uint4 sA[4], sB[2];

    auto LOAD = [&](int k0) {
#pragma unroll
        for (int u = 0; u < 4; u++) {
            int lin = u * 256 + tid;
            int row = lin >> 3, c8 = (lin & 7) << 3;
            sA[u] = *(const uint4*)(Sb + (size_t)(ti + row) * 256 + k0 + c8);
        }
#pragma unroll
        for (int u = 0; u < 2; u++) {
            int lin = u * 256 + tid;
            int row = lin >> 3, c8 = (lin & 7) << 3;
            sB[u] = *(const uint4*)(Vtb + (size_t)(d0 + row) * 256 + k0 + c8);
        }
    };

    auto WRITE = [&](int buf) {
#pragma unroll
        for (int u = 0; u < 4; u++) {
            int lin = u * 256 + tid;
            int row = lin >> 3, c8 = (lin & 7) << 3;
            *(uint4*)(&Als[buf][row * 72 + c8]) = sA[u];
        }
#pragma unroll
        for (int u = 0; u < 2; u++) {
            int lin = u * 256 + tid;
            int row = lin >> 3, c8 = (lin & 7) << 3;
            *(uint4*)(&Bls[buf][row * 72 + c8]) = sB[u];
        }
    };

    auto COMPUTE = [&](int buf) {
        __builtin_amdgcn_s_setprio(1);
#pragma unroll
        for (int kk = 0; kk < 64; kk += 32) {
            bf16x8 af[4], bfr[2];
#pragma unroll
            for (int mi = 0; mi < 4; mi++)
                af[mi] = *(const bf16x8*)(&Als[buf][(m0 + mi * 16 + lr) * 72 + kk + lg * 8]);
#pragma unroll
            for (int ni = 0; ni < 2; ni++)
                bfr[ni] = *(const bf16x8*)(&Bls[buf][(n0 + ni * 16 + lr) * 72 + kk + lg * 8]);
#pragma unroll
            for (int mi = 0; mi < 4; mi++)
#pragma unroll
                for (int ni = 0; ni < 2; ni++)
                    acc[mi][ni] = __builtin_amdgcn_mfma_f32_16x16x32_bf16(
                        af[mi], bfr[ni], acc[mi][ni], 0, 0, 0);
        }
        __builtin_amdgcn_s_setprio(0);
    };

    auto BAR = [&]() {
        asm volatile("s_waitcnt lgkmcnt(0)" ::: "memory");
        __builtin_amdgcn_s_barrier();
        asm volatile("" ::: "memory");
    };

    LOAD(0);
    WRITE(0);
    BAR();

    int cur = 0;
    for (int t = 0; t < 3; t++) {
        LOAD((t + 1) * 64);
        COMPUTE(cur);
        WRITE(cur ^ 1);
        BAR();
        cur ^= 1;
    }
    COMPUTE(cur);

    float* ob = out + (size_t)bh * 65536;
#pragma unroll
    for (int mi = 0; mi < 4; mi++) {
        int tr = ti + m0 + mi * 16 + lg * 4;
#pragma unroll
        for (int ni = 0; ni < 2; ni++) {
            int dc = d0 + n0 + ni * 16 + lr;
#pragma unroll
            for (int r = 0; r < 4; r++)
                ob[(size_t)(tr + r) * 256 + dc] = acc[mi][ni][r];
        }
    }
}

// ---------------------------------------------------------------------------
extern "C" void kernel_launch(void* const* d_in, const int* in_sizes, int n_in,
                              void* d_out, int out_size, void* d_ws, size_t ws_size,
                              hipStream_t stream) {
    const float* Q = (const float*)d_in[0];
    const float* K = (const float*)d_in[1];
    const float* V = (const float*)d_in[2];
    float* out = (float*)d_out;

    unsigned* cs = (unsigned*)d_ws;                                       // 32 KB
    unsigned short* scores = (unsigned short*)((char*)d_ws + 32768);      // 8 MB
    unsigned short* Vt = (unsigned short*)((char*)d_ws + 32768 + 8388608);// 2 MB

    build_cs<<<dim3(32), dim3(256), 0, stream>>>(cs);
    vtrans<<<dim3(256), dim3(256), 0, stream>>>(V, Vt);
    gemm1<<<dim3(512), dim3(512), 0, stream>>>(Q, K, cs, scores);
    gemm2<<<dim3(512), dim3(256), 0, stream>>>(scores, Vt, out);
}

// Round 5
// 131.763 us; speedup vs baseline: 1.2720x; 1.2720x over previous
//
#include <hip/hip_runtime.h>
#include <hip/hip_bf16.h>

#define T_  256
#define NN_ 2048

typedef short bf16x8 __attribute__((ext_vector_type(8)));
typedef float f32x4  __attribute__((ext_vector_type(4)));

__device__ __forceinline__ unsigned short f2bf(float x) {
    union { float f; unsigned u; } v; v.f = x;
    unsigned r = v.u + 0x7fffu + ((v.u >> 16) & 1u);   // RTNE, finite inputs
    return (unsigned short)(r >> 16);
}
__device__ __forceinline__ float bflo(unsigned w) {
    union { unsigned u; float f; } v; v.u = w << 16; return v.f;
}
__device__ __forceinline__ float bfhi(unsigned w) {
    union { unsigned u; float f; } v; v.u = w & 0xffff0000u; return v.f;
}
__device__ __forceinline__ unsigned pkbf(float lo, float hi) {
    union { __hip_bfloat16 h; unsigned short s; } a, b;
    a.h = __float2bfloat16(lo);
    b.h = __float2bfloat16(hi);
    return (unsigned)a.s | ((unsigned)b.s << 16);
}

// ---------------------------------------------------------------------------
// cs[p*512+f] = packed bf16 (cos,sin) of 2*pi*frac(p * 10000^(-f/512)).
// Token t, channel n: p = (bit9(n)? t&15 : t>>4), f = n & 511.
// ---------------------------------------------------------------------------
__global__ void build_cs(unsigned* __restrict__ cs) {
    int idx = blockIdx.x * 256 + threadIdx.x;     // 8192 entries
    int p = idx >> 9, f = idx & 511;
    float inv = powf(10000.0f, -(float)f * (1.0f / 512.0f));
    float ph  = (float)p * inv;
    float ang = (ph - floorf(ph)) * 6.28318530717958647692f;
    float s, c;
    sincosf(ang, &s, &c);
    cs[idx] = pkbf(c, s);
}

// ---------------------------------------------------------------------------
// vtrans: V fp32 (16,256,256) -> Vt bf16 [b][d][s]  (2.1 MB).
// ---------------------------------------------------------------------------
__global__ void vtrans(const float* __restrict__ V, unsigned short* __restrict__ Vt) {
    __shared__ unsigned short Tl[64 * 72];
    const int tid = threadIdx.x;
    const int b  = blockIdx.x >> 4;
    const int s0 = ((blockIdx.x >> 2) & 3) << 6;
    const int d0 = (blockIdx.x & 3) << 6;
    const float* Vb = V + (size_t)b * 65536;
#pragma unroll
    for (int u = 0; u < 4; u++) {
        int lin = u * 256 + tid;
        int srow = lin >> 4, c4 = (lin & 15) << 2;
        float4 v = *(const float4*)(Vb + (size_t)(s0 + srow) * 256 + d0 + c4);
        Tl[(c4 + 0) * 72 + srow] = f2bf(v.x);
        Tl[(c4 + 1) * 72 + srow] = f2bf(v.y);
        Tl[(c4 + 2) * 72 + srow] = f2bf(v.z);
        Tl[(c4 + 3) * 72 + srow] = f2bf(v.w);
    }
    __syncthreads();
    unsigned short* Vtb = Vt + (size_t)b * 65536;
#pragma unroll
    for (int u = 0; u < 2; u++) {
        int lin = u * 256 + tid;
        int drow = lin >> 3, sc8 = (lin & 7) << 3;
        *(uint4*)(Vtb + (size_t)(d0 + drow) * 256 + s0 + sc8) =
            *(const uint4*)(&Tl[drow * 72 + sc8]);
    }
}

// ---------------------------------------------------------------------------
// gemm1: scores = RoPE(Q).RoPE(K)^T / sqrt(N).
// 128x64 tile, BK=64, 512 threads (8 waves), 512 blocks = 2 blocks/CU.
// Depth-2 reg prefetch with sched_barrier pinning (anti-sink); cs sub-table
// (4 KB/slab) double-buffered in LDS via T14 split staging; lgkm-only
// barrier; setprio around MFMA.
// ---------------------------------------------------------------------------
struct QKSet { float4 a[4]; float4 b[2]; };

__launch_bounds__(512, 4)
__global__ void gemm1(const float* __restrict__ Q, const float* __restrict__ K,
                      const unsigned* __restrict__ cs, unsigned short* __restrict__ scores) {
    __shared__ __align__(16) unsigned short Als[2][128 * 72];   // 36 KB
    __shared__ __align__(16) unsigned short Bls[2][64 * 72];    // 18 KB
    __shared__ __align__(16) unsigned csl[2][1024];             //  8 KB

    const int tid  = threadIdx.x;
    const int bh   = blockIdx.x & 63;          // bh%8 fixed per XCD
    const int tile = blockIdx.x >> 6;          // 0..7
    const int ti = (tile >> 2) << 7;           // 0,128      (Q rows)
    const int si = (tile & 3) << 6;            // 0..192     (K rows)

    const float* Qb = Q + (size_t)bh * (T_ * NN_);
    const float* Kb = K + (size_t)bh * (T_ * NN_);

    // staging geometry: thread owns 8-float octs.  A: 2 units, B: 1 unit.
    const float* qpA[2]; int phA[2], pwA[2], c8A[2], ldsA[2];
    const float* qpB0;   int phB, pwB, c8B, ldsB0;
#pragma unroll
    for (int u = 0; u < 2; u++) {
        int lin = u * 512 + tid;
        int row = lin >> 3, c8 = (lin & 7) << 3;
        int gr = ti + row;
        qpA[u] = Qb + (size_t)gr * NN_ + c8;
        phA[u] = gr >> 4;  pwA[u] = gr & 15;
        c8A[u] = c8;       ldsA[u] = row * 72 + c8;
    }
    {
        int row = tid >> 3, c8 = (tid & 7) << 3;
        int gr = si + row;
        qpB0 = Kb + (size_t)gr * NN_ + c8;
        phB = gr >> 4;  pwB = gr & 15;
        c8B = c8;       ldsB0 = row * 72 + c8;
    }

    // cs staging geometry: thread loads one uint2 of the 1024-entry sub-table
    const int csE = tid * 2;
    const int csP = csE >> 6, csC = csE & 63;

    const int wv = tid >> 6, lane = tid & 63;
    const int lr = lane & 15, lg = lane >> 4;
    const int m0 = (wv >> 1) << 5;             // 0,32,64,96
    const int n0 = (wv & 1) << 5;              // 0,32

    f32x4 acc[2][2];
#pragma unroll
    for (int i = 0; i < 2; i++)
#pragma unroll
        for (int j = 0; j < 2; j++) acc[i][j] = (f32x4){0.f, 0.f, 0.f, 0.f};

    auto LOAD = [&](QKSet& s, int slab) {
        const int k0 = slab << 6;
#pragma unroll
        for (int u = 0; u < 2; u++) {
            s.a[2*u]   = *(const float4*)(qpA[u] + k0);
            s.a[2*u+1] = *(const float4*)(qpA[u] + k0 + 4);
        }
        s.b[0] = *(const float4*)(qpB0 + k0);
        s.b[1] = *(const float4*)(qpB0 + k0 + 4);
    };

    auto CSLOADG = [&](uint2& cr, int slab) {      // global -> reg
        const int fk = (slab << 6) & 511;
        cr = *(const uint2*)(cs + (csP << 9) + fk + csC);
    };
    auto CSWRITE = [&](int par, const uint2& cr) { // reg -> LDS
        *(uint2*)(&csl[par][csE]) = cr;
    };
    auto CSSTD = [&](int par, int slab) {          // direct (prologue only)
        const int fk = (slab << 6) & 511;
        *(uint2*)(&csl[par][csE]) = *(const uint2*)(cs + (csP << 9) + fk + csC);
    };

    auto ROT = [&](const float4& f0, const float4& f1,
                   const uint4& u0, const uint4& u1) -> uint4 {
        uint4 o;
        o.x = pkbf(f0.x*bflo(u0.x) - f0.y*bfhi(u0.x),
                   f0.y*bflo(u0.y) + f0.x*bfhi(u0.y));
        o.y = pkbf(f0.z*bflo(u0.z) - f0.w*bfhi(u0.z),
                   f0.w*bflo(u0.w) + f0.z*bfhi(u0.w));
        o.z = pkbf(f1.x*bflo(u1.x) - f1.y*bfhi(u1.x),
                   f1.y*bflo(u1.y) + f1.x*bfhi(u1.y));
        o.w = pkbf(f1.z*bflo(u1.z) - f1.w*bfhi(u1.z),
                   f1.w*bflo(u1.w) + f1.z*bfhi(u1.w));
        return o;
    };

    auto WRITE = [&](int buf, int par, const QKSet& s, int slab) {
        const int w = (slab >> 3) & 1;
#pragma unroll
        for (int u = 0; u < 2; u++) {
            const unsigned* cp = &csl[par][((w ? pwA[u] : phA[u]) << 6) + c8A[u]];
            uint4 u0 = *(const uint4*)cp, u1 = *(const uint4*)(cp + 4);
            *(uint4*)(&Als[buf][ldsA[u]]) = ROT(s.a[2*u], s.a[2*u+1], u0, u1);
        }
        const unsigned* cp = &csl[par][((w ? pwB : phB) << 6) + c8B];
        uint4 u0 = *(const uint4*)cp, u1 = *(const uint4*)(cp + 4);
        *(uint4*)(&Bls[buf][ldsB0]) = ROT(s.b[0], s.b[1], u0, u1);
    };

    auto COMPUTE = [&](int buf) {
        __builtin_amdgcn_s_setprio(1);
#pragma unroll
        for (int kk = 0; kk < 64; kk += 32) {
            bf16x8 af[2], bfr[2];
#pragma unroll
            for (int mi = 0; mi < 2; mi++)
                af[mi] = *(const bf16x8*)(&Als[buf][(m0 + mi * 16 + lr) * 72 + kk + lg * 8]);
#pragma unroll
            for (int ni = 0; ni < 2; ni++)
                bfr[ni] = *(const bf16x8*)(&Bls[buf][(n0 + ni * 16 + lr) * 72 + kk + lg * 8]);
#pragma unroll
            for (int mi = 0; mi < 2; mi++)
#pragma unroll
                for (int ni = 0; ni < 2; ni++)
                    acc[mi][ni] = __builtin_amdgcn_mfma_f32_16x16x32_bf16(
                        af[mi], bfr[ni], acc[mi][ni], 0, 0, 0);
        }
        __builtin_amdgcn_s_setprio(0);
    };

    auto BAR = [&]() {
        asm volatile("s_waitcnt lgkmcnt(0)" ::: "memory");
        __builtin_amdgcn_s_barrier();
        asm volatile("" ::: "memory");
    };

    QKSet s0, s1; uint2 cr0, cr1;

    // prologue
    LOAD(s0, 0);
    LOAD(s1, 1);
    CSSTD(0, 0);
    CSSTD(1, 1);
    CSLOADG(cr0, 2);
    CSLOADG(cr1, 3);
    __builtin_amdgcn_sched_barrier(0);
    BAR();                              // csl[0]=slab0, csl[1]=slab1 visible
    WRITE(0, 0, s0, 0);                 // slab 0 -> buf0
    LOAD(s0, 2);
    __builtin_amdgcn_sched_barrier(0);
    BAR();

    // main loop: steps t = 0..29 (15 double-iterations)
#pragma unroll 1
    for (int t2 = 0; t2 < 15; t2++) {
        const int t = t2 * 2;
        // step t (even, cur=0)
        COMPUTE(0);                     // slab t
        WRITE(1, 1, s1, t + 1);         // slab t+1 (s1 loaded at step t-2)
        CSWRITE(0, cr0);                // cs slab t+2 -> parity 0
        {
            int s3 = t + 3; if (s3 > 31) s3 = 31;
            int s4 = t + 4; if (s4 > 31) s4 = 31;
            LOAD(s1, s3);
            CSLOADG(cr0, s4);
        }
        __builtin_amdgcn_sched_barrier(0);
        BAR();
        // step t+1 (odd, cur=1)
        COMPUTE(1);                     // slab t+1
        WRITE(0, 0, s0, t + 2);         // slab t+2 (s0 loaded at step t-1)
        CSWRITE(1, cr1);                // cs slab t+3 -> parity 1
        {
            int s4 = t + 4; if (s4 > 31) s4 = 31;
            int s5 = t + 5; if (s5 > 31) s5 = 31;
            LOAD(s0, s4);
            CSLOADG(cr1, s5);
        }
        __builtin_amdgcn_sched_barrier(0);
        BAR();
    }
    // t = 30
    COMPUTE(0);                         // slab 30
    WRITE(1, 1, s1, 31);                // slab 31
    BAR();
    // t = 31
    COMPUTE(1);                         // slab 31

    // epilogue: scale, cast bf16, store scores[bh][t][s]
    const float rs = 0.02209708691207961f;   // 1/sqrt(2048)
    unsigned short* sb = scores + (size_t)bh * (T_ * T_);
#pragma unroll
    for (int mi = 0; mi < 2; mi++) {
        int tr = ti + m0 + mi * 16 + lg * 4;
#pragma unroll
        for (int ni = 0; ni < 2; ni++) {
            int sc = si + n0 + ni * 16 + lr;
#pragma unroll
            for (int r = 0; r < 4; r++)
                sb[(size_t)(tr + r) * 256 + sc] = f2bf(acc[mi][ni][r] * rs);
        }
    }
}

// ---------------------------------------------------------------------------
// gemm2: out = scores @ V.  A = scores bf16 row-major, B = Vt bf16 [d][s].
// 128x64 tile, 256 threads, 512 blocks = 2 blocks/CU.
// ---------------------------------------------------------------------------
__launch_bounds__(256, 2)
__global__ void gemm2(const unsigned short* __restrict__ scores,
                      const unsigned short* __restrict__ Vt, float* __restrict__ out) {
    __shared__ __align__(16) unsigned short Als[2][128 * 72];
    __shared__ __align__(16) unsigned short Bls[2][64 * 72];

    const int tid  = threadIdx.x;
    const int bh   = blockIdx.x & 63;
    const int b    = bh >> 2;
    const int tile = blockIdx.x >> 6;          // 0..7
    const int ti = (tile >> 2) << 7;           // 0,128   (t rows)
    const int d0 = (tile & 3) << 6;            // 0..192  (d cols)

    const unsigned short* Sb  = scores + (size_t)bh * 65536;
    const unsigned short* Vtb = Vt + (size_t)b * 65536;

    const int wv = tid >> 6, lane = tid & 63;
    const int lr = lane & 15, lg = lane >> 4;
    const int m0 = (wv >> 1) * 64;
    const int n0 = (wv & 1) * 32;

    f32x4 acc[4][2];
#pragma unroll
    for (int i = 0; i < 4; i++)
#pragma unroll
        for (int j = 0; j < 2; j++) acc[i][j] = (f32x4){0.f, 0.f, 0.f, 0.f};

    uint4 sA[4], sB[2];

    auto LOAD = [&](int k0) {
#pragma unroll
        for (int u = 0; u < 4; u++) {
            int lin = u * 256 + tid;
            int row = lin >> 3, c8 = (lin & 7) << 3;
            sA[u] = *(const uint4*)(Sb + (size_t)(ti + row) * 256 + k0 + c8);
        }
#pragma unroll
        for (int u = 0; u < 2; u++) {
            int lin = u * 256 + tid;
            int row = lin >> 3, c8 = (lin & 7) << 3;
            sB[u] = *(const uint4*)(Vtb + (size_t)(d0 + row) * 256 + k0 + c8);
        }
    };

    auto WRITE = [&](int buf) {
#pragma unroll
        for (int u = 0; u < 4; u++) {
            int lin = u * 256 + tid;
            int row = lin >> 3, c8 = (lin & 7) << 3;
            *(uint4*)(&Als[buf][row * 72 + c8]) = sA[u];
        }
#pragma unroll
        for (int u = 0; u < 2; u++) {
            int lin = u * 256 + tid;
            int row = lin >> 3, c8 = (lin & 7) << 3;
            *(uint4*)(&Bls[buf][row * 72 + c8]) = sB[u];
        }
    };

    auto COMPUTE = [&](int buf) {
        __builtin_amdgcn_s_setprio(1);
#pragma unroll
        for (int kk = 0; kk < 64; kk += 32) {
            bf16x8 af[4], bfr[2];
#pragma unroll
            for (int mi = 0; mi < 4; mi++)
                af[mi] = *(const bf16x8*)(&Als[buf][(m0 + mi * 16 + lr) * 72 + kk + lg * 8]);
#pragma unroll
            for (int ni = 0; ni < 2; ni++)
                bfr[ni] = *(const bf16x8*)(&Bls[buf][(n0 + ni * 16 + lr) * 72 + kk + lg * 8]);
#pragma unroll
            for (int mi = 0; mi < 4; mi++)
#pragma unroll
                for (int ni = 0; ni < 2; ni++)
                    acc[mi][ni] = __builtin_amdgcn_mfma_f32_16x16x32_bf16(
                        af[mi], bfr[ni], acc[mi][ni], 0, 0, 0);
        }
        __builtin_amdgcn_s_setprio(0);
    };

    auto BAR = [&]() {
        asm volatile("s_waitcnt lgkmcnt(0)" ::: "memory");
        __builtin_amdgcn_s_barrier();
        asm volatile("" ::: "memory");
    };

    LOAD(0);
    WRITE(0);
    BAR();

    int cur = 0;
#pragma unroll 1
    for (int t = 0; t < 3; t++) {
        LOAD((t + 1) * 64);
        COMPUTE(cur);
        WRITE(cur ^ 1);
        __builtin_amdgcn_sched_barrier(0);
        BAR();
        cur ^= 1;
    }
    COMPUTE(cur);

    float* ob = out + (size_t)bh * 65536;
#pragma unroll
    for (int mi = 0; mi < 4; mi++) {
        int tr = ti + m0 + mi * 16 + lg * 4;
#pragma unroll
        for (int ni = 0; ni < 2; ni++) {
            int dc = d0 + n0 + ni * 16 + lr;
#pragma unroll
            for (int r = 0; r < 4; r++)
                ob[(size_t)(tr + r) * 256 + dc] = acc[mi][ni][r];
        }
    }
}

// ---------------------------------------------------------------------------
extern "C" void kernel_launch(void* const* d_in, const int* in_sizes, int n_in,
                              void* d_out, int out_size, void* d_ws, size_t ws_size,
                              hipStream_t stream) {
    const float* Q = (const float*)d_in[0];
    const float* K = (const float*)d_in[1];
    const float* V = (const float*)d_in[2];
    float* out = (float*)d_out;

    unsigned* cs = (unsigned*)d_ws;                                       // 32 KB
    unsigned short* scores = (unsigned short*)((char*)d_ws + 32768);      // 8 MB
    unsigned short* Vt = (unsigned short*)((char*)d_ws + 32768 + 8388608);// 2 MB

    build_cs<<<dim3(32), dim3(256), 0, stream>>>(cs);
    vtrans<<<dim3(256), dim3(256), 0, stream>>>(V, Vt);
    gemm1<<<dim3(512), dim3(512), 0, stream>>>(Q, K, cs, scores);
    gemm2<<<dim3(512), dim3(256), 0, stream>>>(scores, Vt, out);
}